// Round 1
// baseline (456.088 us; speedup 1.0000x reference)
//
#include <hip/hip_runtime.h>
#include <math.h>

#define NI 100000   // N_ITEMS
#define NB 512      // batch
#define NH 256      // hidden H
#define H3 768      // 3*H
#define LL 3

// ---------------- layer-0 x_proj: gather of W_ih0 columns ----------------
__global__ void k_gather_xp0(const int* __restrict__ idx,
                             const float* __restrict__ Wih0,   // (768, NI)
                             const float* __restrict__ bih0,   // (768)
                             float* __restrict__ xp)           // (512, 768)
{
    const int b = blockIdx.x;
    const int ib = idx[b];
    for (int j = threadIdx.x; j < H3; j += 256) {
        xp[b * H3 + j] = Wih0[(size_t)j * NI + ib] + bih0[j];
    }
}

// ---------------- GRU gate elementwise ----------------
__global__ void k_gates(const float* __restrict__ xp,     // (512,768)
                        const float* __restrict__ hp,     // (512,768)
                        const float* __restrict__ hprev,  // (512,256)
                        float* __restrict__ hnew)         // (512,256)
{
    const int t = blockIdx.x * 256 + threadIdx.x;   // 0 .. 131071
    const int b = t >> 8;
    const int j = t & 255;
    const float xr = xp[b * H3 + j];
    const float xz = xp[b * H3 + NH + j];
    const float xn = xp[b * H3 + 2 * NH + j];
    const float hr = hp[b * H3 + j];
    const float hz = hp[b * H3 + NH + j];
    const float hn = hp[b * H3 + 2 * NH + j];
    const float h  = hprev[t];
    const float r = 1.0f / (1.0f + expf(-(xr + hr)));
    const float z = 1.0f / (1.0f + expf(-(xz + hz)));
    const float n = tanhf(xn + r * hn);
    hnew[t] = (1.0f - z) * n + z * h;
}

// ---------------- tiled fp32 GEMM:  C[m][n] = sum_k A[m][k]*B[n][k] + bias[n], opt tanh ----
// A row-major (M,K); B row-major (N,K); C row-major with leading dim ldc.
// 256 threads as 16x16; each thread TMxTN micro-tile (split-half layout for 8x8).
// LDS tiles stored K-major with XOR swizzle on m-index: phys_m = m ^ (((k>>2)&3)<<3)
// -> transpose staging stores are 2-way bank aliased (free), reads stay float4.
template<int BM, int BN, int TM, int TN, bool TANH>
__global__ __launch_bounds__(256)
void k_gemm_abt(const float* __restrict__ A,
                const float* __restrict__ Bm,
                const float* __restrict__ bias,
                float* __restrict__ C,
                int M, int N, int K, int ldc)
{
    constexpr int BK = 32;
    __shared__ float As[BK][BM];
    __shared__ float Bs[BK][BN];

    const int tid = threadIdx.x;
    const int tx  = tid & 15;
    const int ty  = tid >> 4;
    const int m0  = blockIdx.x * BM;   // M-fastest grid: adjacent blocks share B panel
    const int n0  = blockIdx.y * BN;

    float acc[TM][TN];
#pragma unroll
    for (int i = 0; i < TM; i++)
#pragma unroll
        for (int j = 0; j < TN; j++) acc[i][j] = 0.0f;

    for (int k0 = 0; k0 < K; k0 += BK) {
        // ---- stage A tile (BM x BK) transposed+swizzled ----
#pragma unroll
        for (int f = 0; f < BM * BK / 1024; f++) {
            const int fid = tid + f * 256;
            const int row = fid >> 3;        // 8 float4 per row of 32 k's
            const int t4  = fid & 7;
            const float4 v = *(const float4*)(A + (size_t)(m0 + row) * K + k0 + t4 * 4);
            const int mp = row ^ ((t4 & 3) << 3);
            As[t4 * 4 + 0][mp] = v.x;
            As[t4 * 4 + 1][mp] = v.y;
            As[t4 * 4 + 2][mp] = v.z;
            As[t4 * 4 + 3][mp] = v.w;
        }
        // ---- stage B tile (BN x BK), zero-fill past N ----
#pragma unroll
        for (int f = 0; f < BN * BK / 1024; f++) {
            const int fid = tid + f * 256;
            const int row = fid >> 3;
            const int t4  = fid & 7;
            const int gn  = n0 + row;
            float4 v = make_float4(0.f, 0.f, 0.f, 0.f);
            if (gn < N) v = *(const float4*)(Bm + (size_t)gn * K + k0 + t4 * 4);
            const int mp = row ^ ((t4 & 3) << 3);
            Bs[t4 * 4 + 0][mp] = v.x;
            Bs[t4 * 4 + 1][mp] = v.y;
            Bs[t4 * 4 + 2][mp] = v.z;
            Bs[t4 * 4 + 3][mp] = v.w;
        }
        __syncthreads();

#pragma unroll
        for (int kk = 0; kk < BK; kk++) {
            const int s = ((kk >> 2) & 3) << 3;
            float av[TM], bv[TN];
            const float4 a0 = *(const float4*)&As[kk][(ty * 4) ^ s];
            av[0] = a0.x; av[1] = a0.y; av[2] = a0.z; av[3] = a0.w;
            if constexpr (TM == 8) {
                const float4 a1 = *(const float4*)&As[kk][BM / 2 + ((ty * 4) ^ s)];
                av[4] = a1.x; av[5] = a1.y; av[6] = a1.z; av[7] = a1.w;
            }
            const float4 b0 = *(const float4*)&Bs[kk][(tx * 4) ^ s];
            bv[0] = b0.x; bv[1] = b0.y; bv[2] = b0.z; bv[3] = b0.w;
            if constexpr (TN == 8) {
                const float4 b1 = *(const float4*)&Bs[kk][BN / 2 + ((tx * 4) ^ s)];
                bv[4] = b1.x; bv[5] = b1.y; bv[6] = b1.z; bv[7] = b1.w;
            }
#pragma unroll
            for (int i = 0; i < TM; i++)
#pragma unroll
                for (int j = 0; j < TN; j++)
                    acc[i][j] = fmaf(av[i], bv[j], acc[i][j]);
        }
        __syncthreads();
    }

    // ---- epilogue: bias (+tanh), float4 stores, bounds-checked on N ----
#pragma unroll
    for (int i = 0; i < TM; i++) {
        const int mi = (i < 4) ? (ty * 4 + i) : (BM / 2 + ty * 4 + (i - 4));
        const size_t rowoff = (size_t)(m0 + mi) * ldc;
#pragma unroll
        for (int jg = 0; jg < TN / 4; jg++) {
            const int nj = (jg == 0) ? (tx * 4) : (BN / 2 + tx * 4);
            const int gn = n0 + nj;
            if (gn < N) {   // gn multiple of 4, N multiple of 4
                const float4 bb = *(const float4*)(bias + gn);
                float4 v;
                v.x = acc[i][jg * 4 + 0] + bb.x;
                v.y = acc[i][jg * 4 + 1] + bb.y;
                v.z = acc[i][jg * 4 + 2] + bb.z;
                v.w = acc[i][jg * 4 + 3] + bb.w;
                if (TANH) {
                    v.x = tanhf(v.x); v.y = tanhf(v.y);
                    v.z = tanhf(v.z); v.w = tanhf(v.w);
                }
                *(float4*)(C + rowoff + gn) = v;
            }
        }
    }
}

extern "C" void kernel_launch(void* const* d_in, const int* in_sizes, int n_in,
                              void* d_out, int out_size, void* d_ws, size_t ws_size,
                              hipStream_t stream)
{
    const int*   idx    = (const int*)  d_in[0];
    const float* hidden = (const float*)d_in[1];   // (3,512,256)
    const float* Wih0   = (const float*)d_in[2];   // (768,100000)
    const float* WihHi  = (const float*)d_in[3];   // (2,768,256)
    const float* Whh    = (const float*)d_in[4];   // (3,768,256)
    const float* bih    = (const float*)d_in[5];   // (3,768)
    const float* bhh    = (const float*)d_in[6];   // (3,768)
    const float* Wout   = (const float*)d_in[7];   // (100000,256)
    const float* bout   = (const float*)d_in[8];   // (100000)

    float* act  = (float*)d_out;                  // (512, NI)
    float* hnew = act + (size_t)NB * NI;          // (3,512,256)
    // Scratch lives in the activation region; final GEMM overwrites it.
    float* xp = act;                              // (512,768)
    float* hp = act + NB * H3;                    // (512,768)

    const dim3 bs(256);
    const dim3 gsmall(NB / 64, H3 / 64);          // (8,12)

    // ---- layer 0 ----
    k_gather_xp0<<<NB, 256, 0, stream>>>(idx, Wih0, bih, xp);
    k_gemm_abt<64, 64, 4, 4, false><<<gsmall, bs, 0, stream>>>(
        hidden, Whh, bhh, hp, NB, H3, NH, H3);
    k_gates<<<NB, 256, 0, stream>>>(xp, hp, hidden, hnew);

    // ---- layer 1 ----
    k_gemm_abt<64, 64, 4, 4, false><<<gsmall, bs, 0, stream>>>(
        hnew, WihHi, bih + H3, xp, NB, H3, NH, H3);
    k_gemm_abt<64, 64, 4, 4, false><<<gsmall, bs, 0, stream>>>(
        hidden + NB * NH, Whh + H3 * NH, bhh + H3, hp, NB, H3, NH, H3);
    k_gates<<<NB, 256, 0, stream>>>(xp, hp, hidden + NB * NH, hnew + NB * NH);

    // ---- layer 2 ----
    k_gemm_abt<64, 64, 4, 4, false><<<gsmall, bs, 0, stream>>>(
        hnew + NB * NH, WihHi + H3 * NH, bih + 2 * H3, xp, NB, H3, NH, H3);
    k_gemm_abt<64, 64, 4, 4, false><<<gsmall, bs, 0, stream>>>(
        hidden + 2 * NB * NH, Whh + 2 * H3 * NH, bhh + 2 * H3, hp, NB, H3, NH, H3);
    k_gates<<<NB, 256, 0, stream>>>(xp, hp, hidden + 2 * NB * NH, hnew + 2 * NB * NH);

    // ---- output projection: act = tanh(x @ Wout.T + bout) ----
    k_gemm_abt<128, 128, 8, 8, true><<<dim3(NB / 128, (NI + 127) / 128), bs, 0, stream>>>(
        hnew + 2 * NB * NH, Wout, bout, act, NB, NI, NH, NI);
}

// Round 2
// 321.024 us; speedup vs baseline: 1.4207x; 1.4207x over previous
//
#include <hip/hip_runtime.h>
#include <math.h>

#define NI 100000   // N_ITEMS
#define NB 512      // batch
#define NH 256      // hidden H
#define H3 768      // 3*H

typedef _Float16 f16x8 __attribute__((ext_vector_type(8)));
typedef float    f32x4 __attribute__((ext_vector_type(4)));

// ---------------- GRU gate elementwise (layer 0: gather x_proj inline) ----------------
__global__ void k_gates0(const int* __restrict__ idx,
                         const float* __restrict__ Wih0,   // (768, NI)
                         const float* __restrict__ bih0,   // (768)
                         const float* __restrict__ hp,     // (512,768)
                         const float* __restrict__ hprev,  // (512,256)
                         float* __restrict__ hnew)         // (512,256)
{
    const int b = blockIdx.x;
    const int j = threadIdx.x;          // 0..255
    const int ib = idx[b];
    const float xr = Wih0[(size_t)(j          ) * NI + ib] + bih0[j];
    const float xz = Wih0[(size_t)(j + NH     ) * NI + ib] + bih0[j + NH];
    const float xn = Wih0[(size_t)(j + 2 * NH ) * NI + ib] + bih0[j + 2 * NH];
    const float hr = hp[b * H3 + j];
    const float hz = hp[b * H3 + NH + j];
    const float hn = hp[b * H3 + 2 * NH + j];
    const float h  = hprev[b * NH + j];
    const float r = 1.0f / (1.0f + expf(-(xr + hr)));
    const float z = 1.0f / (1.0f + expf(-(xz + hz)));
    const float n = tanhf(xn + r * hn);
    hnew[b * NH + j] = (1.0f - z) * n + z * h;
}

// ---------------- GRU gate elementwise (layers 1,2) ----------------
__global__ void k_gates(const float* __restrict__ xp,     // (512,768)
                        const float* __restrict__ hp,     // (512,768)
                        const float* __restrict__ hprev,  // (512,256)
                        float* __restrict__ hnew)         // (512,256)
{
    const int b = blockIdx.x;
    const int j = threadIdx.x;
    const float xr = xp[b * H3 + j];
    const float xz = xp[b * H3 + NH + j];
    const float xn = xp[b * H3 + 2 * NH + j];
    const float hr = hp[b * H3 + j];
    const float hz = hp[b * H3 + NH + j];
    const float hn = hp[b * H3 + 2 * NH + j];
    const float h  = hprev[b * NH + j];
    const float r = 1.0f / (1.0f + expf(-(xr + hr)));
    const float z = 1.0f / (1.0f + expf(-(xz + hz)));
    const float n = tanhf(xn + r * hn);
    hnew[b * NH + j] = (1.0f - z) * n + z * h;
}

// ---------------- small tiled fp32 GEMM:  C = A @ B.T + bias (z-batched) ----------------
// A row-major (M,K); B row-major (N,K); C row-major ld=N. 64x64 tile, 4x4 micro.
__global__ __launch_bounds__(256)
void k_gemm_small(const float* __restrict__ A0,
                  const float* __restrict__ B0,
                  const float* __restrict__ bias0,
                  float* __restrict__ C0,
                  int M, int N, int K,
                  int sA, int sB, int sBias, int sC)
{
    constexpr int BM = 64, BN = 64, BK = 32;
    __shared__ float As[BK][BM];
    __shared__ float Bs[BK][BN];

    const float* A    = A0 + (size_t)blockIdx.z * sA;
    const float* Bm   = B0 + (size_t)blockIdx.z * sB;
    const float* bias = bias0 + (size_t)blockIdx.z * sBias;
    float*       C    = C0 + (size_t)blockIdx.z * sC;

    const int tid = threadIdx.x;
    const int tx  = tid & 15;
    const int ty  = tid >> 4;
    const int m0  = blockIdx.x * BM;
    const int n0  = blockIdx.y * BN;

    float acc[4][4];
#pragma unroll
    for (int i = 0; i < 4; i++)
#pragma unroll
        for (int j = 0; j < 4; j++) acc[i][j] = 0.0f;

    for (int k0 = 0; k0 < K; k0 += BK) {
#pragma unroll
        for (int f = 0; f < 2; f++) {
            const int fid = tid + f * 256;
            const int row = fid >> 3;
            const int t4  = fid & 7;
            const int mp  = row ^ ((t4 & 3) << 3);
            {
                const float4 v = *(const float4*)(A + (size_t)(m0 + row) * K + k0 + t4 * 4);
                As[t4 * 4 + 0][mp] = v.x; As[t4 * 4 + 1][mp] = v.y;
                As[t4 * 4 + 2][mp] = v.z; As[t4 * 4 + 3][mp] = v.w;
            }
            {
                const float4 v = *(const float4*)(Bm + (size_t)(n0 + row) * K + k0 + t4 * 4);
                Bs[t4 * 4 + 0][mp] = v.x; Bs[t4 * 4 + 1][mp] = v.y;
                Bs[t4 * 4 + 2][mp] = v.z; Bs[t4 * 4 + 3][mp] = v.w;
            }
        }
        __syncthreads();
#pragma unroll
        for (int kk = 0; kk < BK; kk++) {
            const int s = ((kk >> 2) & 3) << 3;
            const float4 a0 = *(const float4*)&As[kk][(ty * 4) ^ s];
            const float4 b0 = *(const float4*)&Bs[kk][(tx * 4) ^ s];
            const float av[4] = {a0.x, a0.y, a0.z, a0.w};
            const float bv[4] = {b0.x, b0.y, b0.z, b0.w};
#pragma unroll
            for (int i = 0; i < 4; i++)
#pragma unroll
                for (int j = 0; j < 4; j++)
                    acc[i][j] = fmaf(av[i], bv[j], acc[i][j]);
        }
        __syncthreads();
    }

#pragma unroll
    for (int i = 0; i < 4; i++) {
        const size_t rowoff = (size_t)(m0 + ty * 4 + i) * N;
        const int gn = n0 + tx * 4;
        const float4 bb = *(const float4*)(bias + gn);
        float4 v;
        v.x = acc[i][0] + bb.x; v.y = acc[i][1] + bb.y;
        v.z = acc[i][2] + bb.z; v.w = acc[i][3] + bb.w;
        *(float4*)(C + rowoff + gn) = v;
    }
}

// ---------------- output projection: act = tanh(x @ Wout.T + bout), fp16 MFMA ----------
// BM=512 (whole batch, 8 waves x 64 rows), BN=128 per block. No LDS: A and B loaded
// directly as MFMA fragments (both operands 8-contiguous-k per lane, row = lane&15;
// C layout col=lane&15, row=(lane>>4)*4+reg  [m89-verified]).
__global__ __launch_bounds__(512, 2)
void k_out_mfma(const float* __restrict__ X,     // (512,256)
                const float* __restrict__ W,     // (NI,256)
                const float* __restrict__ bout,  // (NI)
                float* __restrict__ C)           // (512,NI)
{
    const int n0   = blockIdx.x * 128;
    const int tid  = threadIdx.x;
    const int w    = tid >> 6;        // wave 0..7 -> rows [w*64, w*64+64)
    const int lane = tid & 63;
    const int lr   = lane & 15;
    const int lg   = lane >> 4;       // 0..3

    f32x4 acc[8][4];
#pragma unroll
    for (int nf = 0; nf < 8; nf++)
#pragma unroll
        for (int mf = 0; mf < 4; mf++) acc[nf][mf] = (f32x4){0.f, 0.f, 0.f, 0.f};

#pragma unroll 2
    for (int k = 0; k < NH; k += 32) {
        // A fragments for this k-slice: x[w*64+mf*16+lr][k + lg*8 + e]
        f16x8 af[4];
#pragma unroll
        for (int mf = 0; mf < 4; mf++) {
            const float* p = X + (size_t)(w * 64 + mf * 16 + lr) * NH + k + lg * 8;
            const float4 a0 = *(const float4*)p;
            const float4 a1 = *(const float4*)(p + 4);
            f16x8 h;
            h[0] = (_Float16)a0.x; h[1] = (_Float16)a0.y;
            h[2] = (_Float16)a0.z; h[3] = (_Float16)a0.w;
            h[4] = (_Float16)a1.x; h[5] = (_Float16)a1.y;
            h[6] = (_Float16)a1.z; h[7] = (_Float16)a1.w;
            af[mf] = h;
        }
#pragma unroll
        for (int nf = 0; nf < 8; nf++) {
            const int wr = n0 + nf * 16 + lr;
            float4 b0 = make_float4(0.f, 0.f, 0.f, 0.f);
            float4 b1 = b0;
            if (wr < NI) {
                const float* p = W + (size_t)wr * NH + k + lg * 8;
                b0 = *(const float4*)p;
                b1 = *(const float4*)(p + 4);
            }
            f16x8 bf;
            bf[0] = (_Float16)b0.x; bf[1] = (_Float16)b0.y;
            bf[2] = (_Float16)b0.z; bf[3] = (_Float16)b0.w;
            bf[4] = (_Float16)b1.x; bf[5] = (_Float16)b1.y;
            bf[6] = (_Float16)b1.z; bf[7] = (_Float16)b1.w;
#pragma unroll
            for (int mf = 0; mf < 4; mf++)
                acc[nf][mf] = __builtin_amdgcn_mfma_f32_16x16x32_f16(af[mf], bf, acc[nf][mf], 0, 0, 0);
        }
    }

    // epilogue: bias + tanh + scalar stores (16-lane groups are 64B-contiguous)
#pragma unroll
    for (int nf = 0; nf < 8; nf++) {
        const int col = n0 + nf * 16 + lr;
        if (col < NI) {
            const float bb = bout[col];
#pragma unroll
            for (int mf = 0; mf < 4; mf++) {
#pragma unroll
                for (int r = 0; r < 4; r++) {
                    const int row = w * 64 + mf * 16 + lg * 4 + r;
                    C[(size_t)row * NI + col] = tanhf(acc[nf][mf][r] + bb);
                }
            }
        }
    }
}

extern "C" void kernel_launch(void* const* d_in, const int* in_sizes, int n_in,
                              void* d_out, int out_size, void* d_ws, size_t ws_size,
                              hipStream_t stream)
{
    const int*   idx    = (const int*)  d_in[0];
    const float* hidden = (const float*)d_in[1];   // (3,512,256)
    const float* Wih0   = (const float*)d_in[2];   // (768,100000)
    const float* WihHi  = (const float*)d_in[3];   // (2,768,256)
    const float* Whh    = (const float*)d_in[4];   // (3,768,256)
    const float* bih    = (const float*)d_in[5];   // (3,768)
    const float* bhh    = (const float*)d_in[6];   // (3,768)
    const float* Wout   = (const float*)d_in[7];   // (100000,256)
    const float* bout   = (const float*)d_in[8];   // (100000)

    float* act  = (float*)d_out;                  // (512, NI)
    float* hnew = act + (size_t)NB * NI;          // (3,512,256)
    // Scratch lives in the activation region; final GEMM overwrites it.
    float* hp = act;                              // (3,512,768)
    float* xp = act + 3 * NB * H3;                // (512,768)

    const dim3 bs(256);
    const dim3 gs_hp(NB / 64, H3 / 64, 3);        // all 3 h@Whh.T upfront (independent)
    const dim3 gs_xp(NB / 64, H3 / 64, 1);

    // ---- all hidden-projections (depend only on input `hidden`) ----
    k_gemm_small<<<gs_hp, bs, 0, stream>>>(hidden, Whh, bhh, hp,
                                           NB, H3, NH, NB * NH, H3 * NH, H3, NB * H3);
    // ---- layer 0 (x_proj gathered inline) ----
    k_gates0<<<NB, bs, 0, stream>>>(idx, Wih0, bih, hp, hidden, hnew);
    // ---- layer 1 ----
    k_gemm_small<<<gs_xp, bs, 0, stream>>>(hnew, WihHi, bih + H3, xp,
                                           NB, H3, NH, 0, 0, 0, 0);
    k_gates<<<NB, bs, 0, stream>>>(xp, hp + NB * H3, hidden + NB * NH, hnew + NB * NH);
    // ---- layer 2 ----
    k_gemm_small<<<gs_xp, bs, 0, stream>>>(hnew + NB * NH, WihHi + H3 * NH, bih + 2 * H3, xp,
                                           NB, H3, NH, 0, 0, 0, 0);
    k_gates<<<NB, bs, 0, stream>>>(xp, hp + 2 * NB * H3, hidden + 2 * NB * NH, hnew + 2 * NB * NH);

    // ---- output projection ----
    k_out_mfma<<<dim3((NI + 127) / 128), dim3(512), 0, stream>>>(
        hnew + 2 * NB * NH, Wout, bout, act);
}

// Round 3
// 218.694 us; speedup vs baseline: 2.0855x; 1.4679x over previous
//
#include <hip/hip_runtime.h>
#include <math.h>
#include <stdint.h>

#define NI 100000   // N_ITEMS
#define NB 512      // batch
#define NH 256      // hidden H
#define H3 768      // 3*H

typedef _Float16 f16x8 __attribute__((ext_vector_type(8)));
typedef float    f32x4 __attribute__((ext_vector_type(4)));

__device__ __forceinline__ float tanh_fast(float x) {
    x = fminf(fmaxf(x, -9.0f), 9.0f);
    const float e = __expf(2.0f * x);
    return (e - 1.0f) * __builtin_amdgcn_rcpf(e + 1.0f);
}

// ---------------- GRU gate elementwise (layer 0: gather x_proj inline) ----------------
__global__ void k_gates0(const int* __restrict__ idx,
                         const float* __restrict__ Wih0,   // (768, NI)
                         const float* __restrict__ bih0,   // (768)
                         const float* __restrict__ hp,     // (512,768)
                         const float* __restrict__ hprev,  // (512,256)
                         float* __restrict__ hnew)         // (512,256)
{
    const int b = blockIdx.x;
    const int j = threadIdx.x;          // 0..255
    const int ib = idx[b];
    const float xr = Wih0[(size_t)(j          ) * NI + ib] + bih0[j];
    const float xz = Wih0[(size_t)(j + NH     ) * NI + ib] + bih0[j + NH];
    const float xn = Wih0[(size_t)(j + 2 * NH ) * NI + ib] + bih0[j + 2 * NH];
    const float hr = hp[b * H3 + j];
    const float hz = hp[b * H3 + NH + j];
    const float hn = hp[b * H3 + 2 * NH + j];
    const float h  = hprev[b * NH + j];
    const float r = 1.0f / (1.0f + expf(-(xr + hr)));
    const float z = 1.0f / (1.0f + expf(-(xz + hz)));
    const float n = tanhf(xn + r * hn);
    hnew[b * NH + j] = (1.0f - z) * n + z * h;
}

// ---------------- GRU gate elementwise (layer 1) ----------------
__global__ void k_gates(const float* __restrict__ xp,
                        const float* __restrict__ hp,
                        const float* __restrict__ hprev,
                        float* __restrict__ hnew)
{
    const int b = blockIdx.x;
    const int j = threadIdx.x;
    const float xr = xp[b * H3 + j];
    const float xz = xp[b * H3 + NH + j];
    const float xn = xp[b * H3 + 2 * NH + j];
    const float hr = hp[b * H3 + j];
    const float hz = hp[b * H3 + NH + j];
    const float hn = hp[b * H3 + 2 * NH + j];
    const float h  = hprev[b * NH + j];
    const float r = 1.0f / (1.0f + expf(-(xr + hr)));
    const float z = 1.0f / (1.0f + expf(-(xz + hz)));
    const float n = tanhf(xn + r * hn);
    hnew[b * NH + j] = (1.0f - z) * n + z * h;
}

// ---------------- layer 2 gates: also emit fp16 copy of h2 for the MFMA GEMM --------
__global__ void k_gates_last(const float* __restrict__ xp,
                             const float* __restrict__ hp,
                             const float* __restrict__ hprev,
                             float* __restrict__ hnew,
                             _Float16* __restrict__ Xh)    // (512,256) fp16
{
    const int b = blockIdx.x;
    const int j = threadIdx.x;
    const float xr = xp[b * H3 + j];
    const float xz = xp[b * H3 + NH + j];
    const float xn = xp[b * H3 + 2 * NH + j];
    const float hr = hp[b * H3 + j];
    const float hz = hp[b * H3 + NH + j];
    const float hn = hp[b * H3 + 2 * NH + j];
    const float h  = hprev[b * NH + j];
    const float r = 1.0f / (1.0f + expf(-(xr + hr)));
    const float z = 1.0f / (1.0f + expf(-(xz + hz)));
    const float n = tanhf(xn + r * hn);
    const float v = (1.0f - z) * n + z * h;
    hnew[b * NH + j] = v;
    Xh[b * NH + j] = (_Float16)v;
}

// ---------------- small tiled fp32 GEMM:  C = A @ B.T + bias (z-batched) ----------------
__global__ __launch_bounds__(256)
void k_gemm_small(const float* __restrict__ A0,
                  const float* __restrict__ B0,
                  const float* __restrict__ bias0,
                  float* __restrict__ C0,
                  int M, int N, int K,
                  int sA, int sB, int sBias, int sC)
{
    constexpr int BM = 64, BN = 64, BK = 32;
    __shared__ float As[BK][BM];
    __shared__ float Bs[BK][BN];

    const float* A    = A0 + (size_t)blockIdx.z * sA;
    const float* Bm   = B0 + (size_t)blockIdx.z * sB;
    const float* bias = bias0 + (size_t)blockIdx.z * sBias;
    float*       C    = C0 + (size_t)blockIdx.z * sC;

    const int tid = threadIdx.x;
    const int tx  = tid & 15;
    const int ty  = tid >> 4;
    const int m0  = blockIdx.x * BM;
    const int n0  = blockIdx.y * BN;

    float acc[4][4];
#pragma unroll
    for (int i = 0; i < 4; i++)
#pragma unroll
        for (int j = 0; j < 4; j++) acc[i][j] = 0.0f;

    for (int k0 = 0; k0 < K; k0 += BK) {
#pragma unroll
        for (int f = 0; f < 2; f++) {
            const int fid = tid + f * 256;
            const int row = fid >> 3;
            const int t4  = fid & 7;
            const int mp  = row ^ ((t4 & 3) << 3);
            {
                const float4 v = *(const float4*)(A + (size_t)(m0 + row) * K + k0 + t4 * 4);
                As[t4 * 4 + 0][mp] = v.x; As[t4 * 4 + 1][mp] = v.y;
                As[t4 * 4 + 2][mp] = v.z; As[t4 * 4 + 3][mp] = v.w;
            }
            {
                const float4 v = *(const float4*)(Bm + (size_t)(n0 + row) * K + k0 + t4 * 4);
                Bs[t4 * 4 + 0][mp] = v.x; Bs[t4 * 4 + 1][mp] = v.y;
                Bs[t4 * 4 + 2][mp] = v.z; Bs[t4 * 4 + 3][mp] = v.w;
            }
        }
        __syncthreads();
#pragma unroll
        for (int kk = 0; kk < BK; kk++) {
            const int s = ((kk >> 2) & 3) << 3;
            const float4 a0 = *(const float4*)&As[kk][(ty * 4) ^ s];
            const float4 b0 = *(const float4*)&Bs[kk][(tx * 4) ^ s];
            const float av[4] = {a0.x, a0.y, a0.z, a0.w};
            const float bv[4] = {b0.x, b0.y, b0.z, b0.w};
#pragma unroll
            for (int i = 0; i < 4; i++)
#pragma unroll
                for (int j = 0; j < 4; j++)
                    acc[i][j] = fmaf(av[i], bv[j], acc[i][j]);
        }
        __syncthreads();
    }

#pragma unroll
    for (int i = 0; i < 4; i++) {
        const size_t rowoff = (size_t)(m0 + ty * 4 + i) * N;
        const int gn = n0 + tx * 4;
        const float4 bb = *(const float4*)(bias + gn);
        float4 v;
        v.x = acc[i][0] + bb.x; v.y = acc[i][1] + bb.y;
        v.z = acc[i][2] + bb.z; v.w = acc[i][3] + bb.w;
        *(float4*)(C + rowoff + gn) = v;
    }
}

// ---------------- output projection: act = tanh(x @ Wout.T + bout), fp16 MFMA ----------
// Block: 512 thr (8 waves, 2M x 4N), tile BM=128 x BN=256, wave tile 64x64.
// W (fp32) staged via global_load_lds into double-buffered LDS with source-side XOR
// chunk swizzle (linear LDS dest, swizzled global src, swizzled ds_read) -> fp16 frags.
// X pre-converted fp16, loaded direct (L2-resident).
// OPERAND SWAP: mfma(A=W-frag, B=X-frag) -> D col(lane&15)=m, row((lane>>4)*4+r)=n
// => per-lane float4 stores of 4 consecutive n. (Layout relabeled from verified r1 kernel.)
__global__ __launch_bounds__(512, 4)
void k_out_mfma(const _Float16* __restrict__ Xh,  // (512,256) fp16
                const float* __restrict__ W,      // (NI,256) fp32
                const float* __restrict__ bout,   // (NI)
                float* __restrict__ C)            // (512,NI)
{
    constexpr int BK = 32;
    __shared__ float Ws[2][256 * BK];    // 2 x 32 KB

    // bijective chunked XCD swizzle: nwg = 1564 = 8*195 + 4  (m204)
    const int bid = blockIdx.x;
    const int xcd = bid & 7, pos = bid >> 3;
    const int q = 195, r4 = 4;
    const int wg = (xcd < r4) ? (xcd * (q + 1) + pos)
                              : (r4 * (q + 1) + (xcd - r4) * q + pos);
    const int my = wg & 3;        // M-tile 0..3  (4 blocks sharing a W panel are adjacent)
    const int ny = wg >> 2;       // N-tile 0..390

    const int n0   = ny * 256;
    const int tid  = threadIdx.x;
    const int w    = tid >> 6;          // wave 0..7
    const int lane = tid & 63;
    const int lr   = lane & 15;
    const int lg   = lane >> 4;         // 0..3
    const int wm   = w >> 2;            // 0..1 (M half)
    const int wn   = w & 3;             // 0..3 (N quad)
    const int m0w  = my * 128 + wm * 64;

    // stage one 256x32 fp32 W tile into Ws[buf]; linear LDS dest, swizzled source
    auto stage = [&](int buf, int k0) {
#pragma unroll
        for (int it = 0; it < 4; ++it) {
            const int fid = it * 512 + tid;       // 0..2047 -> 2048*16B = 32KB
            const int row = fid >> 3;             // 0..255
            const int cl  = fid & 7;              // physical 16B chunk
            const int cg  = cl ^ (row & 7);       // logical chunk fetched here
            const int gr  = (n0 + row < NI) ? (n0 + row) : (NI - 1);
            const float* src = W + (size_t)gr * NH + k0 + cg * 4;
            float* dst = &Ws[buf][fid * 4];
            __builtin_amdgcn_global_load_lds(
                (const __attribute__((address_space(1))) void*)src,
                (__attribute__((address_space(3))) void*)dst,
                16, 0, 0);
        }
    };

    f32x4 acc[4][4];
#pragma unroll
    for (int nf = 0; nf < 4; ++nf)
#pragma unroll
        for (int mf = 0; mf < 4; ++mf) acc[nf][mf] = (f32x4){0.f, 0.f, 0.f, 0.f};

    stage(0, 0);
    __syncthreads();

    for (int t = 0; t < 8; ++t) {
        const int buf = t & 1;
        if (t < 7) stage(buf ^ 1, (t + 1) * BK);
        const int k0 = t * BK;

        // W fragments (A-operand): rows = n, 8 contiguous k per lane
        f16x8 wf[4];
#pragma unroll
        for (int nf = 0; nf < 4; ++nf) {
            const int rl = wn * 64 + nf * 16 + lr;            // 0..255
            const int c0 = (lg * 2)     ^ (rl & 7);
            const int c1 = (lg * 2 + 1) ^ (rl & 7);
            const f32x4 u0 = *(const f32x4*)&Ws[buf][rl * BK + c0 * 4];
            const f32x4 u1 = *(const f32x4*)&Ws[buf][rl * BK + c1 * 4];
            f16x8 h;
            h[0] = (_Float16)u0[0]; h[1] = (_Float16)u0[1];
            h[2] = (_Float16)u0[2]; h[3] = (_Float16)u0[3];
            h[4] = (_Float16)u1[0]; h[5] = (_Float16)u1[1];
            h[6] = (_Float16)u1[2]; h[7] = (_Float16)u1[3];
            wf[nf] = h;
        }
        // X fragments (B-operand): rows = m, fp16 direct (L2-resident)
        f16x8 xf[4];
#pragma unroll
        for (int mf = 0; mf < 4; ++mf)
            xf[mf] = *(const f16x8*)(Xh + (size_t)(m0w + mf * 16 + lr) * NH + k0 + lg * 8);

#pragma unroll
        for (int nf = 0; nf < 4; ++nf)
#pragma unroll
            for (int mf = 0; mf < 4; ++mf)
                acc[nf][mf] = __builtin_amdgcn_mfma_f32_16x16x32_f16(
                    wf[nf], xf[mf], acc[nf][mf], 0, 0, 0);

        __syncthreads();   // drains vmcnt (stage t+1 done) + all ds_reads of buf done
    }

    // epilogue: bias + tanh, per-lane float4 of 4 consecutive n
#pragma unroll
    for (int nf = 0; nf < 4; ++nf) {
        const int nb = n0 + wn * 64 + nf * 16;   // frag base; NI%16==0 -> all-or-none
        if (nb < NI) {
            const float4 bb = *(const float4*)(bout + nb + lg * 4);
#pragma unroll
            for (int mf = 0; mf < 4; ++mf) {
                const int m = m0w + mf * 16 + lr;
                float4 v;
                v.x = tanh_fast(acc[nf][mf][0] + bb.x);
                v.y = tanh_fast(acc[nf][mf][1] + bb.y);
                v.z = tanh_fast(acc[nf][mf][2] + bb.z);
                v.w = tanh_fast(acc[nf][mf][3] + bb.w);
                *(float4*)(C + (size_t)m * NI + nb + lg * 4) = v;
            }
        }
    }
}

extern "C" void kernel_launch(void* const* d_in, const int* in_sizes, int n_in,
                              void* d_out, int out_size, void* d_ws, size_t ws_size,
                              hipStream_t stream)
{
    const int*   idx    = (const int*)  d_in[0];
    const float* hidden = (const float*)d_in[1];   // (3,512,256)
    const float* Wih0   = (const float*)d_in[2];   // (768,100000)
    const float* WihHi  = (const float*)d_in[3];   // (2,768,256)
    const float* Whh    = (const float*)d_in[4];   // (3,768,256)
    const float* bih    = (const float*)d_in[5];   // (3,768)
    const float* bhh    = (const float*)d_in[6];   // (3,768)
    const float* Wout   = (const float*)d_in[7];   // (100000,256)
    const float* bout   = (const float*)d_in[8];   // (100000)

    float* act  = (float*)d_out;                  // (512, NI)
    float* hnew = act + (size_t)NB * NI;          // (3,512,256)
    // fp32 scratch lives in the activation region; final GEMM overwrites it.
    float* hp = act;                              // (3,512,768)
    float* xp = act + 3 * NB * H3;                // (512,768)
    // fp16 X lives in d_ws (must survive while the big GEMM writes act)
    _Float16* Xh = (_Float16*)d_ws;               // (512,256) = 256 KB

    const dim3 bs(256);
    const dim3 gs_hp(NB / 64, H3 / 64, 3);
    const dim3 gs_xp(NB / 64, H3 / 64, 1);

    // ---- all hidden-projections (depend only on input `hidden`) ----
    k_gemm_small<<<gs_hp, bs, 0, stream>>>(hidden, Whh, bhh, hp,
                                           NB, H3, NH, NB * NH, H3 * NH, H3, NB * H3);
    // ---- layer 0 (x_proj gathered inline) ----
    k_gates0<<<NB, bs, 0, stream>>>(idx, Wih0, bih, hp, hidden, hnew);
    // ---- layer 1 ----
    k_gemm_small<<<gs_xp, bs, 0, stream>>>(hnew, WihHi, bih + H3, xp,
                                           NB, H3, NH, 0, 0, 0, 0);
    k_gates<<<NB, bs, 0, stream>>>(xp, hp + NB * H3, hidden + NB * NH, hnew + NB * NH);
    // ---- layer 2 (also emits fp16 h2) ----
    k_gemm_small<<<gs_xp, bs, 0, stream>>>(hnew + NB * NH, WihHi + H3 * NH, bih + 2 * H3, xp,
                                           NB, H3, NH, 0, 0, 0, 0);
    k_gates_last<<<NB, bs, 0, stream>>>(xp, hp + 2 * NB * H3, hidden + 2 * NB * NH,
                                        hnew + 2 * NB * NH, Xh);

    // ---- output projection: 391 N-tiles x 4 M-tiles = 1564 blocks ----
    k_out_mfma<<<dim3(1564), dim3(512), 0, stream>>>(Xh, Wout, bout, act);
}

// Round 4
// 205.162 us; speedup vs baseline: 2.2231x; 1.0660x over previous
//
#include <hip/hip_runtime.h>
#include <math.h>
#include <stdint.h>

#define NI 100000   // N_ITEMS
#define NB 512      // batch
#define NH 256      // hidden H
#define H3 768      // 3*H

typedef _Float16 f16x8 __attribute__((ext_vector_type(8)));
typedef float    f32x4 __attribute__((ext_vector_type(4)));

__device__ __forceinline__ float tanh_fast(float x) {
    x = fminf(fmaxf(x, -9.0f), 9.0f);
    const float e = __expf(2.0f * x);
    return (e - 1.0f) * __builtin_amdgcn_rcpf(e + 1.0f);
}

// ---------------- GRU gate elementwise (layer 0: gather x_proj inline) ----------------
__global__ void k_gates0(const int* __restrict__ idx,
                         const float* __restrict__ Wih0,   // (768, NI)
                         const float* __restrict__ bih0,   // (768)
                         const float* __restrict__ hp,     // (512,768)
                         const float* __restrict__ hprev,  // (512,256)
                         float* __restrict__ hnew)         // (512,256)
{
    const int b = blockIdx.x;
    const int j = threadIdx.x;          // 0..255
    const int ib = idx[b];
    const float xr = Wih0[(size_t)(j          ) * NI + ib] + bih0[j];
    const float xz = Wih0[(size_t)(j + NH     ) * NI + ib] + bih0[j + NH];
    const float xn = Wih0[(size_t)(j + 2 * NH ) * NI + ib] + bih0[j + 2 * NH];
    const float hr = hp[b * H3 + j];
    const float hz = hp[b * H3 + NH + j];
    const float hn = hp[b * H3 + 2 * NH + j];
    const float h  = hprev[b * NH + j];
    const float r = 1.0f / (1.0f + expf(-(xr + hr)));
    const float z = 1.0f / (1.0f + expf(-(xz + hz)));
    const float n = tanhf(xn + r * hn);
    hnew[b * NH + j] = (1.0f - z) * n + z * h;
}

// ---------------- GRU gate elementwise (layer 1) ----------------
__global__ void k_gates(const float* __restrict__ xp,
                        const float* __restrict__ hp,
                        const float* __restrict__ hprev,
                        float* __restrict__ hnew)
{
    const int b = blockIdx.x;
    const int j = threadIdx.x;
    const float xr = xp[b * H3 + j];
    const float xz = xp[b * H3 + NH + j];
    const float xn = xp[b * H3 + 2 * NH + j];
    const float hr = hp[b * H3 + j];
    const float hz = hp[b * H3 + NH + j];
    const float hn = hp[b * H3 + 2 * NH + j];
    const float h  = hprev[b * NH + j];
    const float r = 1.0f / (1.0f + expf(-(xr + hr)));
    const float z = 1.0f / (1.0f + expf(-(xz + hz)));
    const float n = tanhf(xn + r * hn);
    hnew[b * NH + j] = (1.0f - z) * n + z * h;
}

// ---------------- layer 2 gates: also emit fp16 copy of h2 for the MFMA GEMM --------
__global__ void k_gates_last(const float* __restrict__ xp,
                             const float* __restrict__ hp,
                             const float* __restrict__ hprev,
                             float* __restrict__ hnew,
                             _Float16* __restrict__ Xh)    // (512,256) fp16
{
    const int b = blockIdx.x;
    const int j = threadIdx.x;
    const float xr = xp[b * H3 + j];
    const float xz = xp[b * H3 + NH + j];
    const float xn = xp[b * H3 + 2 * NH + j];
    const float hr = hp[b * H3 + j];
    const float hz = hp[b * H3 + NH + j];
    const float hn = hp[b * H3 + 2 * NH + j];
    const float h  = hprev[b * NH + j];
    const float r = 1.0f / (1.0f + expf(-(xr + hr)));
    const float z = 1.0f / (1.0f + expf(-(xz + hz)));
    const float n = tanhf(xn + r * hn);
    const float v = (1.0f - z) * n + z * h;
    hnew[b * NH + j] = v;
    Xh[b * NH + j] = (_Float16)v;
}

// ---------------- small tiled fp32 GEMM:  C = A @ B.T + bias (z-batched) ----------------
__global__ __launch_bounds__(256)
void k_gemm_small(const float* __restrict__ A0,
                  const float* __restrict__ B0,
                  const float* __restrict__ bias0,
                  float* __restrict__ C0,
                  int M, int N, int K,
                  int sA, int sB, int sBias, int sC)
{
    constexpr int BM = 64, BN = 64, BK = 32;
    __shared__ float As[BK][BM];
    __shared__ float Bs[BK][BN];

    const float* A    = A0 + (size_t)blockIdx.z * sA;
    const float* Bm   = B0 + (size_t)blockIdx.z * sB;
    const float* bias = bias0 + (size_t)blockIdx.z * sBias;
    float*       C    = C0 + (size_t)blockIdx.z * sC;

    const int tid = threadIdx.x;
    const int tx  = tid & 15;
    const int ty  = tid >> 4;
    const int m0  = blockIdx.x * BM;
    const int n0  = blockIdx.y * BN;

    float acc[4][4];
#pragma unroll
    for (int i = 0; i < 4; i++)
#pragma unroll
        for (int j = 0; j < 4; j++) acc[i][j] = 0.0f;

    for (int k0 = 0; k0 < K; k0 += BK) {
#pragma unroll
        for (int f = 0; f < 2; f++) {
            const int fid = tid + f * 256;
            const int row = fid >> 3;
            const int t4  = fid & 7;
            const int mp  = row ^ ((t4 & 3) << 3);
            {
                const float4 v = *(const float4*)(A + (size_t)(m0 + row) * K + k0 + t4 * 4);
                As[t4 * 4 + 0][mp] = v.x; As[t4 * 4 + 1][mp] = v.y;
                As[t4 * 4 + 2][mp] = v.z; As[t4 * 4 + 3][mp] = v.w;
            }
            {
                const float4 v = *(const float4*)(Bm + (size_t)(n0 + row) * K + k0 + t4 * 4);
                Bs[t4 * 4 + 0][mp] = v.x; Bs[t4 * 4 + 1][mp] = v.y;
                Bs[t4 * 4 + 2][mp] = v.z; Bs[t4 * 4 + 3][mp] = v.w;
            }
        }
        __syncthreads();
#pragma unroll
        for (int kk = 0; kk < BK; kk++) {
            const int s = ((kk >> 2) & 3) << 3;
            const float4 a0 = *(const float4*)&As[kk][(ty * 4) ^ s];
            const float4 b0 = *(const float4*)&Bs[kk][(tx * 4) ^ s];
            const float av[4] = {a0.x, a0.y, a0.z, a0.w};
            const float bv[4] = {b0.x, b0.y, b0.z, b0.w};
#pragma unroll
            for (int i = 0; i < 4; i++)
#pragma unroll
                for (int j = 0; j < 4; j++)
                    acc[i][j] = fmaf(av[i], bv[j], acc[i][j]);
        }
        __syncthreads();
    }

#pragma unroll
    for (int i = 0; i < 4; i++) {
        const size_t rowoff = (size_t)(m0 + ty * 4 + i) * N;
        const int gn = n0 + tx * 4;
        const float4 bb = *(const float4*)(bias + gn);
        float4 v;
        v.x = acc[i][0] + bb.x; v.y = acc[i][1] + bb.y;
        v.z = acc[i][2] + bb.z; v.w = acc[i][3] + bb.w;
        *(float4*)(C + rowoff + gn) = v;
    }
}

// ---------------- output projection: act = tanh(x @ Wout.T + bout), fp16 MFMA ----------
// 256 thr (4 waves, 2M x 2N), tile BM=128 x BN=128, wave tile 64x64, BK=32, dbuf LDS
// 2x16KB. W (fp32) staged via global_load_lds, source-side 16B-chunk XOR swizzle
// (linear LDS dest + inverse-swizzled global src + swizzled ds_read — both-sides rule).
// X pre-converted fp16, direct loads (L2-resident). mfma(A=W-frag, B=X-frag):
// D col(lane&15)=m, row((lane>>4)*4+r)=n -> per-lane float4 stores of 4 consecutive n.
// Math/swizzle identical to the round-3 kernel (test-verified); resized 256->128 rows,
// launch_bounds relaxed to kill the unified-VGPR spill (acc=64 AGPR + ~50 VGPR).
__global__ __launch_bounds__(256, 3)
void k_out_mfma(const _Float16* __restrict__ Xh,  // (512,256) fp16
                const float* __restrict__ W,      // (NI,256) fp32
                const float* __restrict__ bout,   // (NI)
                float* __restrict__ C)            // (512,NI)
{
    constexpr int BK = 32;
    __shared__ float Ws[2][128 * BK];    // 2 x 16 KB

    // bijective chunked XCD swizzle: nwg = 3128 = 8*391 exactly (m204)
    const int bid = blockIdx.x;
    const int xcd = bid & 7, pos = bid >> 3;
    const int wg  = xcd * 391 + pos;
    const int my  = wg & 3;        // M-tile 0..3 (4 blocks sharing a W panel stay on one XCD)
    const int ny  = wg >> 2;       // N-tile 0..781

    const int n0   = ny * 128;
    const int tid  = threadIdx.x;
    const int w    = tid >> 6;          // wave 0..3
    const int lane = tid & 63;
    const int lr   = lane & 15;
    const int lg   = lane >> 4;         // 0..3
    const int wm   = w >> 1;            // 0..1 (M half)
    const int wn   = w & 1;             // 0..1 (N half)
    const int m0w  = my * 128 + wm * 64;

    // stage one 128x32 fp32 W tile into Ws[buf]; linear LDS dest, swizzled source
    auto stage = [&](int buf, int k0) {
#pragma unroll
        for (int it = 0; it < 4; ++it) {
            const int fid = it * 256 + tid;       // 0..1023 -> 1024*16B = 16KB
            const int row = fid >> 3;             // 0..127
            const int cl  = fid & 7;              // physical 16B chunk
            const int cg  = cl ^ (row & 7);       // logical chunk fetched here
            const int gr  = (n0 + row < NI) ? (n0 + row) : (NI - 1);
            const float* src = W + (size_t)gr * NH + k0 + cg * 4;
            float* dst = &Ws[buf][fid * 4];
            __builtin_amdgcn_global_load_lds(
                (const __attribute__((address_space(1))) void*)src,
                (__attribute__((address_space(3))) void*)dst,
                16, 0, 0);
        }
    };

    f32x4 acc[4][4];
#pragma unroll
    for (int nf = 0; nf < 4; ++nf)
#pragma unroll
        for (int mf = 0; mf < 4; ++mf) acc[nf][mf] = (f32x4){0.f, 0.f, 0.f, 0.f};

    stage(0, 0);
    __syncthreads();

    for (int t = 0; t < 8; ++t) {
        const int buf = t & 1;
        if (t < 7) stage(buf ^ 1, (t + 1) * BK);
        const int k0 = t * BK;

        // X fragments (B-operand): rows = m, fp16 direct (L2-resident); reused across nf
        f16x8 xf[4];
#pragma unroll
        for (int mf = 0; mf < 4; ++mf)
            xf[mf] = *(const f16x8*)(Xh + (size_t)(m0w + mf * 16 + lr) * NH + k0 + lg * 8);

        // W fragments (A-operand) built just-in-time per nf: rows = n, 8 contiguous k/lane
#pragma unroll
        for (int nf = 0; nf < 4; ++nf) {
            const int rl = wn * 64 + nf * 16 + lr;            // 0..127
            const int c0 = (lg * 2)     ^ (rl & 7);
            const int c1 = (lg * 2 + 1) ^ (rl & 7);
            const f32x4 u0 = *(const f32x4*)&Ws[buf][rl * BK + c0 * 4];
            const f32x4 u1 = *(const f32x4*)&Ws[buf][rl * BK + c1 * 4];
            f16x8 h;
            h[0] = (_Float16)u0[0]; h[1] = (_Float16)u0[1];
            h[2] = (_Float16)u0[2]; h[3] = (_Float16)u0[3];
            h[4] = (_Float16)u1[0]; h[5] = (_Float16)u1[1];
            h[6] = (_Float16)u1[2]; h[7] = (_Float16)u1[3];
#pragma unroll
            for (int mf = 0; mf < 4; ++mf)
                acc[nf][mf] = __builtin_amdgcn_mfma_f32_16x16x32_f16(
                    h, xf[mf], acc[nf][mf], 0, 0, 0);
        }

        __syncthreads();   // drains vmcnt (stage t+1 done) + all ds_reads of buf done
    }

    // epilogue: bias + tanh, per-lane float4 of 4 consecutive n
#pragma unroll
    for (int nf = 0; nf < 4; ++nf) {
        const int nb = n0 + wn * 64 + nf * 16;   // NI%16==0 -> frag all-in or all-out
        if (nb < NI) {
            const float4 bb = *(const float4*)(bout + nb + lg * 4);
#pragma unroll
            for (int mf = 0; mf < 4; ++mf) {
                const int m = m0w + mf * 16 + lr;
                float4 v;
                v.x = tanh_fast(acc[nf][mf][0] + bb.x);
                v.y = tanh_fast(acc[nf][mf][1] + bb.y);
                v.z = tanh_fast(acc[nf][mf][2] + bb.z);
                v.w = tanh_fast(acc[nf][mf][3] + bb.w);
                *(float4*)(C + (size_t)m * NI + nb + lg * 4) = v;
            }
        }
    }
}

extern "C" void kernel_launch(void* const* d_in, const int* in_sizes, int n_in,
                              void* d_out, int out_size, void* d_ws, size_t ws_size,
                              hipStream_t stream)
{
    const int*   idx    = (const int*)  d_in[0];
    const float* hidden = (const float*)d_in[1];   // (3,512,256)
    const float* Wih0   = (const float*)d_in[2];   // (768,100000)
    const float* WihHi  = (const float*)d_in[3];   // (2,768,256)
    const float* Whh    = (const float*)d_in[4];   // (3,768,256)
    const float* bih    = (const float*)d_in[5];   // (3,768)
    const float* bhh    = (const float*)d_in[6];   // (3,768)
    const float* Wout   = (const float*)d_in[7];   // (100000,256)
    const float* bout   = (const float*)d_in[8];   // (100000)

    float* act  = (float*)d_out;                  // (512, NI)
    float* hnew = act + (size_t)NB * NI;          // (3,512,256)
    // fp32 scratch lives in the activation region; final GEMM overwrites it.
    float* hp = act;                              // (3,512,768)
    float* xp = act + 3 * NB * H3;                // (512,768)
    // fp16 X lives in d_ws (must survive while the big GEMM writes act)
    _Float16* Xh = (_Float16*)d_ws;               // (512,256) = 256 KB

    const dim3 bs(256);
    const dim3 gs_hp(NB / 64, H3 / 64, 3);
    const dim3 gs_xp(NB / 64, H3 / 64, 1);

    // ---- all hidden-projections (depend only on input `hidden`) ----
    k_gemm_small<<<gs_hp, bs, 0, stream>>>(hidden, Whh, bhh, hp,
                                           NB, H3, NH, NB * NH, H3 * NH, H3, NB * H3);
    // ---- layer 0 (x_proj gathered inline) ----
    k_gates0<<<NB, bs, 0, stream>>>(idx, Wih0, bih, hp, hidden, hnew);
    // ---- layer 1 ----
    k_gemm_small<<<gs_xp, bs, 0, stream>>>(hnew, WihHi, bih + H3, xp,
                                           NB, H3, NH, 0, 0, 0, 0);
    k_gates<<<NB, bs, 0, stream>>>(xp, hp + NB * H3, hidden + NB * NH, hnew + NB * NH);
    // ---- layer 2 (also emits fp16 h2) ----
    k_gemm_small<<<gs_xp, bs, 0, stream>>>(hnew + NB * NH, WihHi + H3 * NH, bih + 2 * H3, xp,
                                           NB, H3, NH, 0, 0, 0, 0);
    k_gates_last<<<NB, bs, 0, stream>>>(xp, hp + 2 * NB * H3, hidden + 2 * NB * NH,
                                        hnew + 2 * NB * NH, Xh);

    // ---- output projection: 782 N-tiles x 4 M-tiles = 3128 blocks ----
    k_out_mfma<<<dim3(3128), dim3(256), 0, stream>>>(Xh, Wout, bout, act);
}